// Round 1
// baseline (418.586 us; speedup 1.0000x reference)
//
#include <hip/hip_runtime.h>
#include <math.h>

#define Bb 2
#define Qq 4096
#define Cc 256
#define Nn 6
#define Hh 64
#define Ww 96
#define HEADS 8
#define POINTS 4
#define HW (Hh*Ww)            // 6144
#define BQ (Bb*Qq)            // 8192

// workspace layout (floats)
#define WS_VAL   0                     // [B,N,HW,C]            18,874,368
#define WS_LOCS  18874368              // [B,Q,N,HEADS,POINTS,2] 3,145,728
#define WS_AW    22020096              // [B,Q,N,HEADS,POINTS]   1,572,864
#define WS_REFF  23592960              // [B,N,Q,3]                147,456
#define WS_WSUM  23740416              // [B,Q,C]                2,097,152

// ---------------------------------------------------------------------------
// Kernel R: fisheye reference points + fov mask.  reff[b,n,q] = {refx,refy,fov}
// ---------------------------------------------------------------------------
__global__ void ref_kernel(const float* __restrict__ qc,
                           const float* __restrict__ intr,
                           const float* __restrict__ invE,
                           float* __restrict__ reff) {
    int idx = blockIdx.x * blockDim.x + threadIdx.x;
    if (idx >= BQ) return;
    int b = idx >> 12;
    int q = idx & (Qq - 1);
    float qx = qc[idx*3+0], qy = qc[idx*3+1], qz = qc[idx*3+2];
    float rx = qx * 7.2f - 3.6f;
    float ry = qy * 6.0f - 3.0f;
    float rz = qz * 3.2f - 0.7f;
    for (int n = 0; n < Nn; ++n) {
        const float* E = invE + (b*Nn+n)*16;
        float camx = E[0]*rx + E[1]*ry + E[2]*rz  + E[3];
        float camy = E[4]*rx + E[5]*ry + E[6]*rz  + E[7];
        float camz = E[8]*rx + E[9]*ry + E[10]*rz + E[11];
        const float* K = intr + (b*Nn+n)*9;
        float fx = K[0], cx0 = K[2], cy0 = K[5];
        float r3d   = sqrtf(camx*camx + camy*camy + 1e-8f);
        float theta = atan2f(r3d, camz);
        float phi   = atan2f(camy, camx);
        float r_img = fx * theta;
        float u = r_img * cosf(phi) + cx0;
        float v = r_img * sinf(phi) + cy0;
        float refx = 2.0f * u / 1279.0f - 1.0f;
        float refy = 2.0f * v / 1079.0f - 1.0f;
        float fov = (camz > 0.0f && theta < 1.372f) ? 1.0f : 0.0f;
        int base = ((b*Nn+n)*Qq + q)*3;
        reff[base+0] = refx;
        reff[base+1] = refy;
        reff[base+2] = fov;
    }
}

// ---------------------------------------------------------------------------
// Kernel VP: value projection SGEMM.
// val[bn, pix, c] = sum_k feats[bn, k, pix] * W_val[k, c] + b_val[c]
// 64x64 tile, BK=16, 256 threads, 4x4 per thread.
// ---------------------------------------------------------------------------
__global__ __launch_bounds__(256) void vp_kernel(const float* __restrict__ feats,
                                                 const float* __restrict__ Wv,
                                                 const float* __restrict__ bv,
                                                 float* __restrict__ val) {
    __shared__ __align__(16) float As[16][68];
    __shared__ __align__(16) float Bs[16][68];
    int tid  = threadIdx.x;
    int pix0 = blockIdx.x * 64;
    int col0 = blockIdx.y * 64;
    int bn   = blockIdx.z;
    const float* A = feats + (size_t)bn * Cc * HW;
    int tm = (tid >> 4) << 2;
    int tn = (tid & 15) << 2;
    float acc[4][4] = {};
    for (int k0 = 0; k0 < Cc; k0 += 16) {
        int kk = tid >> 4;
        int xx = (tid & 15) << 2;
        *(float4*)&As[kk][xx] = *(const float4*)&A[(size_t)(k0+kk)*HW + pix0 + xx];
        *(float4*)&Bs[kk][xx] = *(const float4*)&Wv[(size_t)(k0+kk)*Cc + col0 + xx];
        __syncthreads();
#pragma unroll
        for (int k = 0; k < 16; ++k) {
#pragma unroll
            for (int i = 0; i < 4; ++i) {
                float a = As[k][tm+i];
#pragma unroll
                for (int j = 0; j < 4; ++j) acc[i][j] += a * Bs[k][tn+j];
            }
        }
        __syncthreads();
    }
    float4 bias = *(const float4*)&bv[col0 + tn];
#pragma unroll
    for (int i = 0; i < 4; ++i) {
        float4 o;
        o.x = acc[i][0] + bias.x;
        o.y = acc[i][1] + bias.y;
        o.z = acc[i][2] + bias.z;
        o.w = acc[i][3] + bias.w;
        *(float4*)&val[((size_t)bn*HW + pix0 + tm + i)*Cc + col0 + tn] = o;
    }
}

// ---------------------------------------------------------------------------
// Shared GEMM core for row-major A [M,256] @ B [256,ldB], 64x64 tile.
// ---------------------------------------------------------------------------
__device__ __forceinline__ void gemm_acc(const float* __restrict__ A,
                                         const float* __restrict__ Bw,
                                         int ldB, int row0, int col0,
                                         float (&acc)[4][4],
                                         float (&As)[16][68], float (&Bs)[16][68]) {
    int tid = threadIdx.x;
    int tm = (tid >> 4) << 2;
    int tn = (tid & 15) << 2;
    for (int k0 = 0; k0 < 256; k0 += 16) {
        {
            int m  = tid >> 2;
            int kk = (tid & 3) << 2;
            float4 av = *(const float4*)&A[(size_t)(row0+m)*256 + k0 + kk];
            As[kk+0][m] = av.x; As[kk+1][m] = av.y;
            As[kk+2][m] = av.z; As[kk+3][m] = av.w;
        }
        {
            int kb = tid >> 4;
            int nn = (tid & 15) << 2;
            *(float4*)&Bs[kb][nn] = *(const float4*)&Bw[(size_t)(k0+kb)*ldB + col0 + nn];
        }
        __syncthreads();
#pragma unroll
        for (int k = 0; k < 16; ++k) {
#pragma unroll
            for (int i = 0; i < 4; ++i) {
                float a = As[k][tm+i];
#pragma unroll
                for (int j = 0; j < 4; ++j) acc[i][j] += a * Bs[k][tn+j];
            }
        }
        __syncthreads();
    }
}

// ---------------------------------------------------------------------------
// Kernel G1a: offsets GEMM + tanh*0.5 + ref add -> sampling locations.
// cols: j = ((n*8+h)*4+p)*2+xy ; blockIdx.y = camera (64 cols each).
// ---------------------------------------------------------------------------
__global__ __launch_bounds__(256) void g1a_kernel(const float* __restrict__ query,
                                                  const float* __restrict__ W_off,
                                                  const float* __restrict__ b_off,
                                                  const float* __restrict__ reff,
                                                  float* __restrict__ locs) {
    __shared__ __align__(16) float As[16][68];
    __shared__ __align__(16) float Bs[16][68];
    int row0 = blockIdx.x * 64;
    int col0 = blockIdx.y * 64;
    float acc[4][4] = {};
    gemm_acc(query, W_off, 384, row0, col0, acc, As, Bs);
    int tid = threadIdx.x;
    int tm = (tid >> 4) << 2;
    int tn = (tid & 15) << 2;
    int n_cam = blockIdx.y;
    float4 bo = *(const float4*)&b_off[col0 + tn];
    float bof[4] = {bo.x, bo.y, bo.z, bo.w};
#pragma unroll
    for (int i = 0; i < 4; ++i) {
        int r = row0 + tm + i;
        int b = r >> 12;
        int q = r & (Qq - 1);
        int rbase = ((b*Nn + n_cam)*Qq + q)*3;
        float rx = reff[rbase+0];
        float ry = reff[rbase+1];
        float4 o;
        float v0 = tanhf(acc[i][0] + bof[0]) * 0.5f;
        float v1 = tanhf(acc[i][1] + bof[1]) * 0.5f;
        float v2 = tanhf(acc[i][2] + bof[2]) * 0.5f;
        float v3 = tanhf(acc[i][3] + bof[3]) * 0.5f;
        // jj = tn+j ; xy = jj&1 (tn is multiple of 4, so pattern is x,y,x,y)
        o.x = rx + v0; o.y = ry + v1; o.z = rx + v2; o.w = ry + v3;
        *(float4*)&locs[(size_t)r*384 + col0 + tn] = o;
    }
}

// ---------------------------------------------------------------------------
// Kernel G1b: attention GEMM + fov mask + softmax over 4 points.
// cols: j = (n*8+h)*4+p ; each thread owns one aligned group of 4.
// ---------------------------------------------------------------------------
__global__ __launch_bounds__(256) void g1b_kernel(const float* __restrict__ query,
                                                  const float* __restrict__ W_attn,
                                                  const float* __restrict__ b_attn,
                                                  const float* __restrict__ reff,
                                                  float* __restrict__ aw) {
    __shared__ __align__(16) float As[16][68];
    __shared__ __align__(16) float Bs[16][68];
    int row0 = blockIdx.x * 64;
    int col0 = blockIdx.y * 64;
    float acc[4][4] = {};
    gemm_acc(query, W_attn, 192, row0, col0, acc, As, Bs);
    int tid = threadIdx.x;
    int tm = (tid >> 4) << 2;
    int tn = (tid & 15) << 2;
    int j0 = col0 + tn;          // multiple of 4 -> full softmax group
    int n_cam = j0 >> 5;         // 32 cols per camera
    float4 ba = *(const float4*)&b_attn[j0];
    float baf[4] = {ba.x, ba.y, ba.z, ba.w};
#pragma unroll
    for (int i = 0; i < 4; ++i) {
        int r = row0 + tm + i;
        int b = r >> 12;
        int q = r & (Qq - 1);
        float fov = reff[((b*Nn + n_cam)*Qq + q)*3 + 2];
        float l0 = (acc[i][0] + baf[0]) * fov;
        float l1 = (acc[i][1] + baf[1]) * fov;
        float l2 = (acc[i][2] + baf[2]) * fov;
        float l3 = (acc[i][3] + baf[3]) * fov;
        float mx = fmaxf(fmaxf(l0, l1), fmaxf(l2, l3));
        float e0 = expf(l0 - mx), e1 = expf(l1 - mx);
        float e2 = expf(l2 - mx), e3 = expf(l3 - mx);
        float inv = 1.0f / (e0 + e1 + e2 + e3);
        float4 o = {e0*inv, e1*inv, e2*inv, e3*inv};
        *(float4*)&aw[(size_t)r*192 + j0] = o;
    }
}

// ---------------------------------------------------------------------------
// Kernel S: bilinear sampling + attention-weighted sum over (n, p).
// One block per (b,q); thread = head*32 + d  -> coalesced 128B per head.
// ---------------------------------------------------------------------------
__global__ __launch_bounds__(256) void samp_kernel(const float* __restrict__ val,
                                                   const float* __restrict__ locs,
                                                   const float* __restrict__ aw,
                                                   float* __restrict__ wsum) {
    __shared__ float sl[384];
    __shared__ float sa[192];
    int idx = blockIdx.x;            // b*Q + q
    int tid = threadIdx.x;
    sl[tid] = locs[(size_t)idx*384 + tid];
    if (tid < 128) sl[256 + tid] = locs[(size_t)idx*384 + 256 + tid];
    if (tid < 192) sa[tid] = aw[(size_t)idx*192 + tid];
    __syncthreads();
    int b = idx >> 12;
    int head = tid >> 5;
    int d = tid & 31;
    float acc = 0.0f;
    for (int n = 0; n < Nn; ++n) {
        const float* vb = val + (size_t)(b*Nn + n)*HW*Cc + head*32 + d;
#pragma unroll
        for (int p = 0; p < POINTS; ++p) {
            int gbase = (n*HEADS + head)*POINTS + p;
            float x = sl[gbase*2 + 0];
            float y = sl[gbase*2 + 1];
            float w = sa[gbase];
            float gx = (x + 1.0f)*48.0f - 0.5f;   // W/2 = 48
            float gy = (y + 1.0f)*32.0f - 0.5f;   // H/2 = 32
            float x0f = floorf(gx), y0f = floorf(gy);
            float wx = gx - x0f, wy = gy - y0f;
            int ix = (int)x0f, iy = (int)y0f;
            bool vx0 = (unsigned)ix       < (unsigned)Ww;
            bool vx1 = (unsigned)(ix + 1) < (unsigned)Ww;
            bool vy0 = (unsigned)iy       < (unsigned)Hh;
            bool vy1 = (unsigned)(iy + 1) < (unsigned)Hh;
            int ix0c = min(max(ix, 0), Ww-1), ix1c = min(max(ix+1, 0), Ww-1);
            int iy0c = min(max(iy, 0), Hh-1), iy1c = min(max(iy+1, 0), Hh-1);
            float v00 = (vx0 && vy0) ? vb[(size_t)(iy0c*Ww + ix0c)*Cc] : 0.0f;
            float v01 = (vx1 && vy0) ? vb[(size_t)(iy0c*Ww + ix1c)*Cc] : 0.0f;
            float v10 = (vx0 && vy1) ? vb[(size_t)(iy1c*Ww + ix0c)*Cc] : 0.0f;
            float v11 = (vx1 && vy1) ? vb[(size_t)(iy1c*Ww + ix1c)*Cc] : 0.0f;
            float top = v00 + wx*(v01 - v00);
            float bot = v10 + wx*(v11 - v10);
            acc += w * (top + wy*(bot - top));
        }
    }
    wsum[(size_t)idx*256 + tid] = acc;
}

// ---------------------------------------------------------------------------
// Kernel O: output GEMM  out = wsum @ W_out + b_out
// ---------------------------------------------------------------------------
__global__ __launch_bounds__(256) void out_kernel(const float* __restrict__ wsum,
                                                  const float* __restrict__ W_out,
                                                  const float* __restrict__ b_out,
                                                  float* __restrict__ out) {
    __shared__ __align__(16) float As[16][68];
    __shared__ __align__(16) float Bs[16][68];
    int row0 = blockIdx.x * 64;
    int col0 = blockIdx.y * 64;
    float acc[4][4] = {};
    gemm_acc(wsum, W_out, 256, row0, col0, acc, As, Bs);
    int tid = threadIdx.x;
    int tm = (tid >> 4) << 2;
    int tn = (tid & 15) << 2;
    float4 bias = *(const float4*)&b_out[col0 + tn];
#pragma unroll
    for (int i = 0; i < 4; ++i) {
        int r = row0 + tm + i;
        float4 o;
        o.x = acc[i][0] + bias.x;
        o.y = acc[i][1] + bias.y;
        o.z = acc[i][2] + bias.z;
        o.w = acc[i][3] + bias.w;
        *(float4*)&out[(size_t)r*256 + col0 + tn] = o;
    }
}

extern "C" void kernel_launch(void* const* d_in, const int* in_sizes, int n_in,
                              void* d_out, int out_size, void* d_ws, size_t ws_size,
                              hipStream_t stream) {
    const float* query  = (const float*)d_in[0];
    const float* qc     = (const float*)d_in[1];
    const float* feats  = (const float*)d_in[2];
    const float* intr   = (const float*)d_in[3];
    const float* invE   = (const float*)d_in[4];
    const float* W_off  = (const float*)d_in[5];
    const float* b_off  = (const float*)d_in[6];
    const float* W_attn = (const float*)d_in[7];
    const float* b_attn = (const float*)d_in[8];
    const float* W_val  = (const float*)d_in[9];
    const float* b_val  = (const float*)d_in[10];
    const float* W_out  = (const float*)d_in[11];
    const float* b_out  = (const float*)d_in[12];
    float* out  = (float*)d_out;
    float* ws   = (float*)d_ws;
    float* val  = ws + WS_VAL;
    float* locs = ws + WS_LOCS;
    float* aw   = ws + WS_AW;
    float* reff = ws + WS_REFF;
    float* wsum = ws + WS_WSUM;

    hipLaunchKernelGGL(ref_kernel, dim3(BQ/256), dim3(256), 0, stream,
                       qc, intr, invE, reff);
    hipLaunchKernelGGL(vp_kernel, dim3(HW/64, Cc/64, Bb*Nn), dim3(256), 0, stream,
                       feats, W_val, b_val, val);
    hipLaunchKernelGGL(g1a_kernel, dim3(BQ/64, 6), dim3(256), 0, stream,
                       query, W_off, b_off, reff, locs);
    hipLaunchKernelGGL(g1b_kernel, dim3(BQ/64, 3), dim3(256), 0, stream,
                       query, W_attn, b_attn, reff, aw);
    hipLaunchKernelGGL(samp_kernel, dim3(BQ), dim3(256), 0, stream,
                       val, locs, aw, wsum);
    hipLaunchKernelGGL(out_kernel, dim3(BQ/64, Cc/64), dim3(256), 0, stream,
                       wsum, W_out, b_out, out);
}

// Round 2
// 308.464 us; speedup vs baseline: 1.3570x; 1.3570x over previous
//
#include <hip/hip_runtime.h>
#include <math.h>

#define Bb 2
#define Qq 4096
#define Cc 256
#define Nn 6
#define Hh 64
#define Ww 96
#define HEADS 8
#define POINTS 4
#define HW (Hh*Ww)            // 6144
#define BQ (Bb*Qq)            // 8192

// workspace layout (float offsets; val is bf16 now and uses half its old slot)
#define WS_VAL   0                     // bf16 [B,N,HW,C] : 18,874,368 shorts = 9,437,184 floats
#define WS_WT    9437184               // bf16 W_val^T [C][C] : 65,536 shorts = 32,768 floats
#define WS_LOCS  18874368              // [B,Q,N,HEADS,POINTS,2] 3,145,728
#define WS_AW    22020096              // [B,Q,N,HEADS,POINTS]   1,572,864
#define WS_REFF  23592960              // [B,N,Q,3]                147,456
#define WS_WSUM  23740416              // [B,Q,C]                2,097,152

typedef __attribute__((ext_vector_type(8))) short short8;
typedef __attribute__((ext_vector_type(4))) float f32x4;

__device__ __forceinline__ unsigned short f2bf(float f) {
    union { float f; unsigned u; } v; v.f = f;
    unsigned r = (v.u + 0x7fffu + ((v.u >> 16) & 1u)) >> 16;
    return (unsigned short)r;
}
__device__ __forceinline__ float bflo(unsigned u) { return __uint_as_float(u << 16); }
__device__ __forceinline__ float bfhi(unsigned u) { return __uint_as_float(u & 0xffff0000u); }

// ---------------------------------------------------------------------------
// Kernel R: fisheye reference points + fov mask.  reff[b,n,q] = {refx,refy,fov}
// ---------------------------------------------------------------------------
__global__ void ref_kernel(const float* __restrict__ qc,
                           const float* __restrict__ intr,
                           const float* __restrict__ invE,
                           float* __restrict__ reff) {
    int idx = blockIdx.x * blockDim.x + threadIdx.x;
    if (idx >= BQ) return;
    int b = idx >> 12;
    int q = idx & (Qq - 1);
    float qx = qc[idx*3+0], qy = qc[idx*3+1], qz = qc[idx*3+2];
    float rx = qx * 7.2f - 3.6f;
    float ry = qy * 6.0f - 3.0f;
    float rz = qz * 3.2f - 0.7f;
    for (int n = 0; n < Nn; ++n) {
        const float* E = invE + (b*Nn+n)*16;
        float camx = E[0]*rx + E[1]*ry + E[2]*rz  + E[3];
        float camy = E[4]*rx + E[5]*ry + E[6]*rz  + E[7];
        float camz = E[8]*rx + E[9]*ry + E[10]*rz + E[11];
        const float* K = intr + (b*Nn+n)*9;
        float fx = K[0], cx0 = K[2], cy0 = K[5];
        float r3d   = sqrtf(camx*camx + camy*camy + 1e-8f);
        float theta = atan2f(r3d, camz);
        float phi   = atan2f(camy, camx);
        float r_img = fx * theta;
        float u = r_img * cosf(phi) + cx0;
        float v = r_img * sinf(phi) + cy0;
        float refx = 2.0f * u / 1279.0f - 1.0f;
        float refy = 2.0f * v / 1079.0f - 1.0f;
        float fov = (camz > 0.0f && theta < 1.372f) ? 1.0f : 0.0f;
        int base = ((b*Nn+n)*Qq + q)*3;
        reff[base+0] = refx;
        reff[base+1] = refy;
        reff[base+2] = fov;
    }
}

// ---------------------------------------------------------------------------
// Kernel WT: cast+transpose W_val -> Wt[n][k] bf16 (k-contiguous for b-frags)
// ---------------------------------------------------------------------------
__global__ void wt_cast_kernel(const float* __restrict__ Wv,
                               unsigned short* __restrict__ Wt) {
    int idx = blockIdx.x * 256 + threadIdx.x;   // 65536
    int n = idx >> 8, k = idx & 255;
    Wt[idx] = f2bf(Wv[k*256 + n]);
}

// ---------------------------------------------------------------------------
// Kernel VP (MFMA): val[bn, pix, c] = bf16( feats[bn,:,pix] . W_val[:,c] + b_val[c] )
// Block: 64 pixels x 256 cols x full K=256. 512 threads = 8 waves (2m x 4n).
// feats is M-contiguous -> transpose to [m][k] bf16 in LDS during staging.
// ---------------------------------------------------------------------------
__global__ __launch_bounds__(512) void vp_mfma_kernel(const float* __restrict__ feats,
                                                      const unsigned short* __restrict__ Wt,
                                                      const float* __restrict__ bv,
                                                      unsigned short* __restrict__ val) {
    // row = 256 k + 8 pad halfwords = 264 (528 B = 33*16B granules, 16B aligned rows)
    __shared__ __align__(16) unsigned short As[64 * 264];
    int t = threadIdx.x;
    int pix0 = blockIdx.x * 64;
    int bn = blockIdx.y;
    const float* A = feats + (size_t)bn * Cc * HW + pix0;
    // ---- staging: thread t covers m = t&63, k-octet seg = t>>6, 4 iters ----
    int m = t & 63;
    int seg = t >> 6;
    for (int it = 0; it < 4; ++it) {
        int kb = seg * 8 + it * 64;
        float v[8];
#pragma unroll
        for (int j = 0; j < 8; ++j) v[j] = A[(size_t)(kb + j) * HW + m];
        uint4 pk;
        pk.x = (unsigned)f2bf(v[0]) | ((unsigned)f2bf(v[1]) << 16);
        pk.y = (unsigned)f2bf(v[2]) | ((unsigned)f2bf(v[3]) << 16);
        pk.z = (unsigned)f2bf(v[4]) | ((unsigned)f2bf(v[5]) << 16);
        pk.w = (unsigned)f2bf(v[6]) | ((unsigned)f2bf(v[7]) << 16);
        *(uint4*)&As[m * 264 + kb] = pk;
    }
    __syncthreads();
    // ---- compute ----
    int wave = t >> 6, lane = t & 63, quad = lane >> 4, l15 = lane & 15;
    int wm = wave & 1;        // m-half (32 pixels)
    int wn = wave >> 1;       // n-quarter (64 cols)
    f32x4 acc[2][4];
#pragma unroll
    for (int i = 0; i < 2; ++i)
#pragma unroll
        for (int j = 0; j < 4; ++j) acc[i][j] = (f32x4){0.f, 0.f, 0.f, 0.f};
    for (int kk = 0; kk < 8; ++kk) {
        int ko = kk * 32 + quad * 8;
        short8 a0 = *(const short8*)&As[(wm*32 +  0 + l15) * 264 + ko];
        short8 a1 = *(const short8*)&As[(wm*32 + 16 + l15) * 264 + ko];
        short8 bfr[4];
#pragma unroll
        for (int nt = 0; nt < 4; ++nt)
            bfr[nt] = *(const short8*)&Wt[(size_t)(wn*64 + nt*16 + l15) * 256 + ko];
#pragma unroll
        for (int nt = 0; nt < 4; ++nt) {
            acc[0][nt] = __builtin_amdgcn_mfma_f32_16x16x32_bf16(a0, bfr[nt], acc[0][nt], 0, 0, 0);
            acc[1][nt] = __builtin_amdgcn_mfma_f32_16x16x32_bf16(a1, bfr[nt], acc[1][nt], 0, 0, 0);
        }
    }
    // ---- epilogue: C/D layout col=lane&15, row=quad*4+reg ----
#pragma unroll
    for (int nt = 0; nt < 4; ++nt) {
        int n = wn*64 + nt*16 + l15;
        float bias = bv[n];
#pragma unroll
        for (int mt = 0; mt < 2; ++mt) {
#pragma unroll
            for (int r = 0; r < 4; ++r) {
                int mm = wm*32 + mt*16 + quad*4 + r;
                val[((size_t)(bn * HW) + pix0 + mm) * 256 + n] = f2bf(acc[mt][nt][r] + bias);
            }
        }
    }
}

// ---------------------------------------------------------------------------
// Shared fp32 GEMM core for row-major A [M,256] @ B [256,ldB], 64x64 tile.
// ---------------------------------------------------------------------------
__device__ __forceinline__ void gemm_acc(const float* __restrict__ A,
                                         const float* __restrict__ Bw,
                                         int ldB, int row0, int col0,
                                         float (&acc)[4][4],
                                         float (&As)[16][68], float (&Bs)[16][68]) {
    int tid = threadIdx.x;
    int tm = (tid >> 4) << 2;
    int tn = (tid & 15) << 2;
    for (int k0 = 0; k0 < 256; k0 += 16) {
        {
            int m  = tid >> 2;
            int kk = (tid & 3) << 2;
            float4 av = *(const float4*)&A[(size_t)(row0+m)*256 + k0 + kk];
            As[kk+0][m] = av.x; As[kk+1][m] = av.y;
            As[kk+2][m] = av.z; As[kk+3][m] = av.w;
        }
        {
            int kb = tid >> 4;
            int nn = (tid & 15) << 2;
            *(float4*)&Bs[kb][nn] = *(const float4*)&Bw[(size_t)(k0+kb)*ldB + col0 + nn];
        }
        __syncthreads();
#pragma unroll
        for (int k = 0; k < 16; ++k) {
#pragma unroll
            for (int i = 0; i < 4; ++i) {
                float a = As[k][tm+i];
#pragma unroll
                for (int j = 0; j < 4; ++j) acc[i][j] += a * Bs[k][tn+j];
            }
        }
        __syncthreads();
    }
}

// ---------------------------------------------------------------------------
// Kernel G1a: offsets GEMM + tanh*0.5 + ref add -> sampling locations.
// ---------------------------------------------------------------------------
__global__ __launch_bounds__(256) void g1a_kernel(const float* __restrict__ query,
                                                  const float* __restrict__ W_off,
                                                  const float* __restrict__ b_off,
                                                  const float* __restrict__ reff,
                                                  float* __restrict__ locs) {
    __shared__ __align__(16) float As[16][68];
    __shared__ __align__(16) float Bs[16][68];
    int row0 = blockIdx.x * 64;
    int col0 = blockIdx.y * 64;
    float acc[4][4] = {};
    gemm_acc(query, W_off, 384, row0, col0, acc, As, Bs);
    int tid = threadIdx.x;
    int tm = (tid >> 4) << 2;
    int tn = (tid & 15) << 2;
    int n_cam = blockIdx.y;
    float4 bo = *(const float4*)&b_off[col0 + tn];
    float bof[4] = {bo.x, bo.y, bo.z, bo.w};
#pragma unroll
    for (int i = 0; i < 4; ++i) {
        int r = row0 + tm + i;
        int b = r >> 12;
        int q = r & (Qq - 1);
        int rbase = ((b*Nn + n_cam)*Qq + q)*3;
        float rx = reff[rbase+0];
        float ry = reff[rbase+1];
        float4 o;
        float v0 = tanhf(acc[i][0] + bof[0]) * 0.5f;
        float v1 = tanhf(acc[i][1] + bof[1]) * 0.5f;
        float v2 = tanhf(acc[i][2] + bof[2]) * 0.5f;
        float v3 = tanhf(acc[i][3] + bof[3]) * 0.5f;
        o.x = rx + v0; o.y = ry + v1; o.z = rx + v2; o.w = ry + v3;
        *(float4*)&locs[(size_t)r*384 + col0 + tn] = o;
    }
}

// ---------------------------------------------------------------------------
// Kernel G1b: attention GEMM + fov mask + softmax over 4 points.
// ---------------------------------------------------------------------------
__global__ __launch_bounds__(256) void g1b_kernel(const float* __restrict__ query,
                                                  const float* __restrict__ W_attn,
                                                  const float* __restrict__ b_attn,
                                                  const float* __restrict__ reff,
                                                  float* __restrict__ aw) {
    __shared__ __align__(16) float As[16][68];
    __shared__ __align__(16) float Bs[16][68];
    int row0 = blockIdx.x * 64;
    int col0 = blockIdx.y * 64;
    float acc[4][4] = {};
    gemm_acc(query, W_attn, 192, row0, col0, acc, As, Bs);
    int tid = threadIdx.x;
    int tm = (tid >> 4) << 2;
    int tn = (tid & 15) << 2;
    int j0 = col0 + tn;
    int n_cam = j0 >> 5;
    float4 ba = *(const float4*)&b_attn[j0];
    float baf[4] = {ba.x, ba.y, ba.z, ba.w};
#pragma unroll
    for (int i = 0; i < 4; ++i) {
        int r = row0 + tm + i;
        int b = r >> 12;
        int q = r & (Qq - 1);
        float fov = reff[((b*Nn + n_cam)*Qq + q)*3 + 2];
        float l0 = (acc[i][0] + baf[0]) * fov;
        float l1 = (acc[i][1] + baf[1]) * fov;
        float l2 = (acc[i][2] + baf[2]) * fov;
        float l3 = (acc[i][3] + baf[3]) * fov;
        float mx = fmaxf(fmaxf(l0, l1), fmaxf(l2, l3));
        float e0 = expf(l0 - mx), e1 = expf(l1 - mx);
        float e2 = expf(l2 - mx), e3 = expf(l3 - mx);
        float inv = 1.0f / (e0 + e1 + e2 + e3);
        float4 o = {e0*inv, e1*inv, e2*inv, e3*inv};
        *(float4*)&aw[(size_t)r*192 + j0] = o;
    }
}

// ---------------------------------------------------------------------------
// Kernel S: bilinear sampling (bf16 val) + weighted sum.
// One wave per query; 4 channels/lane (packed bf16x2 x2 loads).
// Phase A: 192 samples/query -> premultiplied corner weights + byte offsets in LDS.
// ---------------------------------------------------------------------------
__global__ __launch_bounds__(256) void samp_kernel(const unsigned short* __restrict__ val,
                                                   const float* __restrict__ locs,
                                                   const float* __restrict__ aw,
                                                   float* __restrict__ wsum) {
    __shared__ __align__(16) float swgt[4][192][4];
    __shared__ __align__(16) int   soff[4][192][4];
    int t = threadIdx.x, wv = t >> 6, lane = t & 63;
    int q = blockIdx.x * 4 + wv;
    int b = q >> 12;
#pragma unroll
    for (int j = 0; j < 3; ++j) {
        int s = lane + 64*j;
        float2 xy = *(const float2*)&locs[(size_t)q*384 + 2*s];
        float w = aw[(size_t)q*192 + s];
        float gx = (xy.x + 1.0f)*48.0f - 0.5f;
        float gy = (xy.y + 1.0f)*32.0f - 0.5f;
        float x0f = floorf(gx), y0f = floorf(gy);
        float wx = gx - x0f, wy = gy - y0f;
        int ix = (int)x0f, iy = (int)y0f;
        bool vx0 = (unsigned)ix       < (unsigned)Ww;
        bool vx1 = (unsigned)(ix + 1) < (unsigned)Ww;
        bool vy0 = (unsigned)iy       < (unsigned)Hh;
        bool vy1 = (unsigned)(iy + 1) < (unsigned)Hh;
        int ix0 = min(max(ix, 0), Ww-1), ix1 = min(max(ix+1, 0), Ww-1);
        int iy0 = min(max(iy, 0), Hh-1), iy1 = min(max(iy+1, 0), Hh-1);
        swgt[wv][s][0] = (vx0 && vy0) ? w*(1.0f-wx)*(1.0f-wy) : 0.0f;
        swgt[wv][s][1] = (vx1 && vy0) ? w*wx*(1.0f-wy)        : 0.0f;
        swgt[wv][s][2] = (vx0 && vy1) ? w*(1.0f-wx)*wy        : 0.0f;
        swgt[wv][s][3] = (vx1 && vy1) ? w*wx*wy               : 0.0f;
        soff[wv][s][0] = (iy0*Ww + ix0) * 512;   // pixel byte stride = 256ch*2B
        soff[wv][s][1] = (iy0*Ww + ix1) * 512;
        soff[wv][s][2] = (iy1*Ww + ix0) * 512;
        soff[wv][s][3] = (iy1*Ww + ix1) * 512;
    }
    __syncthreads();
    int head = lane >> 3;
    int c = head*32 + (lane & 7)*4;          // 4 channels per lane
    const char* vbase = (const char*)val + (size_t)b*Nn*HW*512 + c*2;
    float a0 = 0.f, a1 = 0.f, a2 = 0.f, a3 = 0.f;
    for (int n = 0; n < Nn; ++n) {
        const char* vb = vbase + (size_t)n*HW*512;
#pragma unroll
        for (int p = 0; p < POINTS; ++p) {
            int s = (n*HEADS + head)*POINTS + p;
            float4 w4 = *(const float4*)&swgt[wv][s][0];
            int4   o4 = *(const int4*)&soff[wv][s][0];
            {
                uint2 u = *(const uint2*)(vb + o4.x); float w = w4.x;
                a0 += w*bflo(u.x); a1 += w*bfhi(u.x); a2 += w*bflo(u.y); a3 += w*bfhi(u.y);
            }
            {
                uint2 u = *(const uint2*)(vb + o4.y); float w = w4.y;
                a0 += w*bflo(u.x); a1 += w*bfhi(u.x); a2 += w*bflo(u.y); a3 += w*bfhi(u.y);
            }
            {
                uint2 u = *(const uint2*)(vb + o4.z); float w = w4.z;
                a0 += w*bflo(u.x); a1 += w*bfhi(u.x); a2 += w*bflo(u.y); a3 += w*bfhi(u.y);
            }
            {
                uint2 u = *(const uint2*)(vb + o4.w); float w = w4.w;
                a0 += w*bflo(u.x); a1 += w*bfhi(u.x); a2 += w*bflo(u.y); a3 += w*bfhi(u.y);
            }
        }
    }
    float4 o = {a0, a1, a2, a3};
    *(float4*)&wsum[(size_t)q*256 + c] = o;
}

// ---------------------------------------------------------------------------
// Kernel O: output GEMM  out = wsum @ W_out + b_out
// ---------------------------------------------------------------------------
__global__ __launch_bounds__(256) void out_kernel(const float* __restrict__ wsum,
                                                  const float* __restrict__ W_out,
                                                  const float* __restrict__ b_out,
                                                  float* __restrict__ out) {
    __shared__ __align__(16) float As[16][68];
    __shared__ __align__(16) float Bs[16][68];
    int row0 = blockIdx.x * 64;
    int col0 = blockIdx.y * 64;
    float acc[4][4] = {};
    gemm_acc(wsum, W_out, 256, row0, col0, acc, As, Bs);
    int tid = threadIdx.x;
    int tm = (tid >> 4) << 2;
    int tn = (tid & 15) << 2;
    float4 bias = *(const float4*)&b_out[col0 + tn];
#pragma unroll
    for (int i = 0; i < 4; ++i) {
        int r = row0 + tm + i;
        float4 o;
        o.x = acc[i][0] + bias.x;
        o.y = acc[i][1] + bias.y;
        o.z = acc[i][2] + bias.z;
        o.w = acc[i][3] + bias.w;
        *(float4*)&out[(size_t)r*256 + col0 + tn] = o;
    }
}

extern "C" void kernel_launch(void* const* d_in, const int* in_sizes, int n_in,
                              void* d_out, int out_size, void* d_ws, size_t ws_size,
                              hipStream_t stream) {
    const float* query  = (const float*)d_in[0];
    const float* qc     = (const float*)d_in[1];
    const float* feats  = (const float*)d_in[2];
    const float* intr   = (const float*)d_in[3];
    const float* invE   = (const float*)d_in[4];
    const float* W_off  = (const float*)d_in[5];
    const float* b_off  = (const float*)d_in[6];
    const float* W_attn = (const float*)d_in[7];
    const float* b_attn = (const float*)d_in[8];
    const float* W_val  = (const float*)d_in[9];
    const float* b_val  = (const float*)d_in[10];
    const float* W_out  = (const float*)d_in[11];
    const float* b_out  = (const float*)d_in[12];
    float* out = (float*)d_out;
    float* ws  = (float*)d_ws;
    unsigned short* val = (unsigned short*)(ws + WS_VAL);
    unsigned short* Wt  = (unsigned short*)(ws + WS_WT);
    float* locs = ws + WS_LOCS;
    float* aw   = ws + WS_AW;
    float* reff = ws + WS_REFF;
    float* wsum = ws + WS_WSUM;

    hipLaunchKernelGGL(ref_kernel, dim3(BQ/256), dim3(256), 0, stream,
                       qc, intr, invE, reff);
    hipLaunchKernelGGL(wt_cast_kernel, dim3(256), dim3(256), 0, stream,
                       W_val, Wt);
    hipLaunchKernelGGL(vp_mfma_kernel, dim3(HW/64, Bb*Nn), dim3(512), 0, stream,
                       feats, Wt, b_val, val);
    hipLaunchKernelGGL(g1a_kernel, dim3(BQ/64, 6), dim3(256), 0, stream,
                       query, W_off, b_off, reff, locs);
    hipLaunchKernelGGL(g1b_kernel, dim3(BQ/64, 3), dim3(256), 0, stream,
                       query, W_attn, b_attn, reff, aw);
    hipLaunchKernelGGL(samp_kernel, dim3(BQ/4), dim3(256), 0, stream,
                       val, locs, aw, wsum);
    hipLaunchKernelGGL(out_kernel, dim3(BQ/64, Cc/64), dim3(256), 0, stream,
                       wsum, W_out, b_out, out);
}

// Round 3
// 295.868 us; speedup vs baseline: 1.4148x; 1.0426x over previous
//
#include <hip/hip_runtime.h>
#include <math.h>

#define Bb 2
#define Qq 4096
#define Cc 256
#define Nn 6
#define Hh 64
#define Ww 96
#define HEADS 8
#define POINTS 4
#define HW (Hh*Ww)            // 6144
#define BQ (Bb*Qq)            // 8192

// workspace layout (float offsets)
#define WS_VAL   0             // bf16 val [B,N,HW,C]   : 18,874,368 sh = 9,437,184 fl
#define WS_WT    9437184       // bf16 W_val^T [256][256]: 65,536 sh
#define WS_WCH   9469952       // bf16 Wcat^T hi [576][256]: 147,456 sh = 73,728 fl
#define WS_WCL   9543680       // bf16 Wcat^T lo
#define WS_WOT   9617408       // bf16 W_out^T [256][256]
#define WS_LOCS  18874368      // f32 [B,Q,576? no: B,Q,N,H,P,2] = 3,145,728
#define WS_AW    22020096      // f32 [B,Q,192] 1,572,864
#define WS_REFF  23592960      // f32 [B,N,Q,3] 147,456
#define WS_WSUM  23740416      // bf16 [B,Q,C] = 2,097,152 sh = 1,048,576 fl

typedef __attribute__((ext_vector_type(8))) short short8;
typedef __attribute__((ext_vector_type(4))) float f32x4;

__device__ __forceinline__ unsigned short f2bf(float f) {
    union { float f; unsigned u; } v; v.f = f;
    unsigned r = (v.u + 0x7fffu + ((v.u >> 16) & 1u)) >> 16;
    return (unsigned short)r;
}
__device__ __forceinline__ float bf2f(unsigned short h) { return __uint_as_float((unsigned)h << 16); }
__device__ __forceinline__ float bflo(unsigned u) { return __uint_as_float(u << 16); }
__device__ __forceinline__ float bfhi(unsigned u) { return __uint_as_float(u & 0xffff0000u); }

// ---------------------------------------------------------------------------
// Kernel R: fisheye reference points + fov mask.  reff[b,n,q] = {refx,refy,fov}
// ---------------------------------------------------------------------------
__global__ void ref_kernel(const float* __restrict__ qc,
                           const float* __restrict__ intr,
                           const float* __restrict__ invE,
                           float* __restrict__ reff) {
    int idx = blockIdx.x * blockDim.x + threadIdx.x;
    if (idx >= BQ) return;
    int b = idx >> 12;
    int q = idx & (Qq - 1);
    float qx = qc[idx*3+0], qy = qc[idx*3+1], qz = qc[idx*3+2];
    float rx = qx * 7.2f - 3.6f;
    float ry = qy * 6.0f - 3.0f;
    float rz = qz * 3.2f - 0.7f;
    for (int n = 0; n < Nn; ++n) {
        const float* E = invE + (b*Nn+n)*16;
        float camx = E[0]*rx + E[1]*ry + E[2]*rz  + E[3];
        float camy = E[4]*rx + E[5]*ry + E[6]*rz  + E[7];
        float camz = E[8]*rx + E[9]*ry + E[10]*rz + E[11];
        const float* K = intr + (b*Nn+n)*9;
        float fx = K[0], cx0 = K[2], cy0 = K[5];
        float r3d   = sqrtf(camx*camx + camy*camy + 1e-8f);
        float theta = atan2f(r3d, camz);
        float phi   = atan2f(camy, camx);
        float r_img = fx * theta;
        float u = r_img * cosf(phi) + cx0;
        float v = r_img * sinf(phi) + cy0;
        int base = ((b*Nn+n)*Qq + q)*3;
        reff[base+0] = 2.0f * u / 1279.0f - 1.0f;
        reff[base+1] = 2.0f * v / 1079.0f - 1.0f;
        reff[base+2] = (camz > 0.0f && theta < 1.372f) ? 1.0f : 0.0f;
    }
}

// ---------------------------------------------------------------------------
// Kernel C: all weight casts/transposes in one launch.
//  [0,65536)      : Wt      = bf16(W_val^T)        [n][k]
//  [65536,212992) : Wch/Wcl = hi/lo(Wcat^T)        [j][k], j<384 W_off else W_attn
//  [212992,278528): Wot     = bf16(W_out^T)        [n][k]
// ---------------------------------------------------------------------------
__global__ void cast_kernel(const float* __restrict__ Wv,
                            const float* __restrict__ Wo,
                            const float* __restrict__ Wa,
                            const float* __restrict__ Wu,
                            unsigned short* __restrict__ Wt,
                            unsigned short* __restrict__ Wch,
                            unsigned short* __restrict__ Wcl,
                            unsigned short* __restrict__ Wot) {
    int idx = blockIdx.x * 256 + threadIdx.x;
    if (idx < 65536) {
        int n = idx >> 8, k = idx & 255;
        Wt[idx] = f2bf(Wv[k*256 + n]);
    } else if (idx < 212992) {
        int i2 = idx - 65536;
        int j = i2 >> 8, k = i2 & 255;
        float w = (j < 384) ? Wo[k*384 + j] : Wa[k*192 + (j - 384)];
        unsigned short h = f2bf(w);
        Wch[i2] = h;
        Wcl[i2] = f2bf(w - bf2f(h));
    } else if (idx < 278528) {
        int i2 = idx - 212992;
        int n = i2 >> 8, k = i2 & 255;
        Wot[i2] = f2bf(Wu[k*256 + n]);
    }
}

// ---------------------------------------------------------------------------
// Kernel VP (MFMA): val[bn, pix, c] = bf16( feats[bn,:,pix] . W_val[:,c] + b_val[c] )
// 64 pix x 256 cols x K=256.  512 thr = 8 waves (2m x 4n).
// LDS: XOR-swizzled [m][k] bf16 (chunk ^= row&31) -> conflict-free.
// Wt b-frags double-buffered in registers (prefetch kk+1 during MFMA kk).
// ---------------------------------------------------------------------------
__global__ __launch_bounds__(512) void vp_mfma_kernel(const float* __restrict__ feats,
                                                      const unsigned short* __restrict__ Wt,
                                                      const float* __restrict__ bv,
                                                      unsigned short* __restrict__ val) {
    __shared__ __align__(16) unsigned short As[64 * 256];   // 32 KB
    int t = threadIdx.x;
    int pix0 = blockIdx.x * 64;
    int bn = blockIdx.y;
    const float* A = feats + (size_t)bn * Cc * HW + pix0;
    // ---- staging: m = t&63, chunk c = seg + it*8 (8 k-values per chunk) ----
    int m = t & 63;
    int seg = t >> 6;
#pragma unroll
    for (int it = 0; it < 4; ++it) {
        int c = seg + it * 8;
        int kb = c * 8;
        float v[8];
#pragma unroll
        for (int j = 0; j < 8; ++j) v[j] = A[(size_t)(kb + j) * HW + m];
        uint4 pk;
        pk.x = (unsigned)f2bf(v[0]) | ((unsigned)f2bf(v[1]) << 16);
        pk.y = (unsigned)f2bf(v[2]) | ((unsigned)f2bf(v[3]) << 16);
        pk.z = (unsigned)f2bf(v[4]) | ((unsigned)f2bf(v[5]) << 16);
        pk.w = (unsigned)f2bf(v[6]) | ((unsigned)f2bf(v[7]) << 16);
        *(uint4*)&As[m * 256 + ((c ^ (m & 31)) << 3)] = pk;
    }
    __syncthreads();
    // ---- compute ----
    int wave = t >> 6, lane = t & 63, quad = lane >> 4, l15 = lane & 15;
    int wm = wave & 1;
    int wn = wave >> 1;
    int r0 = wm*32 + l15, r1 = r0 + 16;
    const unsigned short* WtW = Wt + (size_t)(wn*64 + l15)*256 + quad*8;
    f32x4 acc[2][4];
#pragma unroll
    for (int i = 0; i < 2; ++i)
#pragma unroll
        for (int j = 0; j < 4; ++j) acc[i][j] = (f32x4){0.f, 0.f, 0.f, 0.f};
    short8 bA[4], bB[4];
#pragma unroll
    for (int nt = 0; nt < 4; ++nt) bA[nt] = *(const short8*)&WtW[nt*4096];
#pragma unroll
    for (int kk = 0; kk < 8; kk += 2) {
        if (kk + 1 < 8) {
#pragma unroll
            for (int nt = 0; nt < 4; ++nt) bB[nt] = *(const short8*)&WtW[nt*4096 + (kk+1)*32];
        }
        {
            short8 a0 = *(const short8*)&As[r0*256 + (((kk*4+quad) ^ (r0 & 31)) << 3)];
            short8 a1 = *(const short8*)&As[r1*256 + (((kk*4+quad) ^ (r1 & 31)) << 3)];
#pragma unroll
            for (int nt = 0; nt < 4; ++nt) {
                acc[0][nt] = __builtin_amdgcn_mfma_f32_16x16x32_bf16(a0, bA[nt], acc[0][nt], 0, 0, 0);
                acc[1][nt] = __builtin_amdgcn_mfma_f32_16x16x32_bf16(a1, bA[nt], acc[1][nt], 0, 0, 0);
            }
        }
        if (kk + 2 < 8) {
#pragma unroll
            for (int nt = 0; nt < 4; ++nt) bA[nt] = *(const short8*)&WtW[nt*4096 + (kk+2)*32];
        }
        if (kk + 1 < 8) {
            int k1 = kk + 1;
            short8 a0 = *(const short8*)&As[r0*256 + (((k1*4+quad) ^ (r0 & 31)) << 3)];
            short8 a1 = *(const short8*)&As[r1*256 + (((k1*4+quad) ^ (r1 & 31)) << 3)];
#pragma unroll
            for (int nt = 0; nt < 4; ++nt) {
                acc[0][nt] = __builtin_amdgcn_mfma_f32_16x16x32_bf16(a0, bB[nt], acc[0][nt], 0, 0, 0);
                acc[1][nt] = __builtin_amdgcn_mfma_f32_16x16x32_bf16(a1, bB[nt], acc[1][nt], 0, 0, 0);
            }
        }
    }
    // ---- epilogue: C/D layout col=lane&15, row=quad*4+reg ----
#pragma unroll
    for (int nt = 0; nt < 4; ++nt) {
        int n = wn*64 + nt*16 + l15;
        float bias = bv[n];
#pragma unroll
        for (int mt = 0; mt < 2; ++mt) {
#pragma unroll
            for (int r = 0; r < 4; ++r) {
                int mm = wm*32 + mt*16 + quad*4 + r;
                val[((size_t)(bn * HW) + pix0 + mm) * 256 + n] = f2bf(acc[mt][nt][r] + bias);
            }
        }
    }
}

// ---------------------------------------------------------------------------
// Kernel QP: fused query projection (offsets + attn), hi/lo bf16 split MFMA
// (3 passes: hh + lh + hl -> fp32-grade precision).
// Block: 32 rows x 576 cols. 512 thr = 8 waves: ms = w&1 (16-row), ng = w>>1
// (9 col-tiles of 16). Epilogue: tanh+ref -> locs ; fov+softmax4 -> aw.
// ---------------------------------------------------------------------------
__global__ __launch_bounds__(512) void qp_kernel(const float* __restrict__ query,
                                                 const unsigned short* __restrict__ Wch,
                                                 const unsigned short* __restrict__ Wcl,
                                                 const float* __restrict__ b_off,
                                                 const float* __restrict__ b_attn,
                                                 const float* __restrict__ reff,
                                                 float* __restrict__ locs,
                                                 float* __restrict__ aw) {
    __shared__ __align__(16) unsigned short Ah[32 * 256];   // 16 KB
    __shared__ __align__(16) unsigned short Al[32 * 256];   // 16 KB
    int t = threadIdx.x;
    int row0 = blockIdx.x * 32;
    // ---- staging: row = t&31, chunk pair c = 2*(t>>5), 2*(t>>5)+1 ----
    {
        int row = t & 31;
        int c2 = t >> 5;
        const float* src = query + (size_t)(row0 + row) * 256;
#pragma unroll
        for (int cc = 0; cc < 2; ++cc) {
            int c = c2 * 2 + cc;
            float4 v0 = *(const float4*)&src[c*8 + 0];
            float4 v1 = *(const float4*)&src[c*8 + 4];
            float f[8] = {v0.x, v0.y, v0.z, v0.w, v1.x, v1.y, v1.z, v1.w};
            unsigned short h[8], l[8];
#pragma unroll
            for (int j = 0; j < 8; ++j) {
                h[j] = f2bf(f[j]);
                l[j] = f2bf(f[j] - bf2f(h[j]));
            }
            uint4 ph, pl;
            ph.x = h[0] | ((unsigned)h[1] << 16); ph.y = h[2] | ((unsigned)h[3] << 16);
            ph.z = h[4] | ((unsigned)h[5] << 16); ph.w = h[6] | ((unsigned)h[7] << 16);
            pl.x = l[0] | ((unsigned)l[1] << 16); pl.y = l[2] | ((unsigned)l[3] << 16);
            pl.z = l[4] | ((unsigned)l[5] << 16); pl.w = l[6] | ((unsigned)l[7] << 16);
            int pos = row * 256 + ((c ^ row) << 3);
            *(uint4*)&Ah[pos] = ph;
            *(uint4*)&Al[pos] = pl;
        }
    }
    __syncthreads();
    int wave = t >> 6, lane = t & 63, quad = lane >> 4, l15 = lane & 15;
    int ms = wave & 1;
    int ng = wave >> 1;
    int arow = ms*16 + l15;
    int bq = row0 >> 12;                 // uniform per block
    // 9 tiles in 3 batches of 3
#pragma unroll
    for (int ib = 0; ib < 3; ++ib) {
        f32x4 acc[3];
#pragma unroll
        for (int i = 0; i < 3; ++i) acc[i] = (f32x4){0.f, 0.f, 0.f, 0.f};
        int col0 = ng*144 + ib*48;
#pragma unroll
        for (int kk = 0; kk < 8; ++kk) {
            int apos = arow*256 + (((kk*4+quad) ^ arow) << 3);
            short8 a_h = *(const short8*)&Ah[apos];
            short8 a_l = *(const short8*)&Al[apos];
            short8 b_h[3], b_l[3];
#pragma unroll
            for (int i = 0; i < 3; ++i) {
                size_t boff = (size_t)(col0 + i*16 + l15)*256 + kk*32 + quad*8;
                b_h[i] = *(const short8*)&Wch[boff];
                b_l[i] = *(const short8*)&Wcl[boff];
            }
#pragma unroll
            for (int i = 0; i < 3; ++i) {
                acc[i] = __builtin_amdgcn_mfma_f32_16x16x32_bf16(a_h, b_h[i], acc[i], 0, 0, 0);
                acc[i] = __builtin_amdgcn_mfma_f32_16x16x32_bf16(a_l, b_h[i], acc[i], 0, 0, 0);
                acc[i] = __builtin_amdgcn_mfma_f32_16x16x32_bf16(a_h, b_l[i], acc[i], 0, 0, 0);
            }
        }
        // ---- epilogue per tile ----
#pragma unroll
        for (int i = 0; i < 3; ++i) {
            int tcol = col0 + i*16;
            int j = tcol + l15;
            if (tcol < 384) {
                // offsets -> locs
                int n_cam = j >> 6;
                int xy = j & 1;
                float bias = b_off[j];
#pragma unroll
                for (int r = 0; r < 4; ++r) {
                    int q = row0 + ms*16 + quad*4 + r;
                    int qq = q & (Qq-1);
                    float refv = reff[((bq*Nn + n_cam)*Qq + qq)*3 + xy];
                    locs[(size_t)q*384 + j] = refv + tanhf(acc[i][r] + bias) * 0.5f;
                }
            } else {
                // attn -> softmax over groups of 4 lanes -> aw
                int j2 = j - 384;
                int n_cam = j2 >> 5;
                float bias = b_attn[j2];
#pragma unroll
                for (int r = 0; r < 4; ++r) {
                    int q = row0 + ms*16 + quad*4 + r;
                    int qq = q & (Qq-1);
                    float fov = reff[((bq*Nn + n_cam)*Qq + qq)*3 + 2];
                    float lg = (acc[i][r] + bias) * fov;
                    float mx = fmaxf(lg, __shfl_xor(lg, 1));
                    mx = fmaxf(mx, __shfl_xor(mx, 2));
                    float e = expf(lg - mx);
                    float s = e + __shfl_xor(e, 1);
                    s = s + __shfl_xor(s, 2);
                    aw[(size_t)q*192 + j2] = e / s;
                }
            }
        }
    }
}

// ---------------------------------------------------------------------------
// Kernel S: bilinear sampling (bf16 val) + weighted sum -> wsum (bf16).
// ---------------------------------------------------------------------------
__global__ __launch_bounds__(256) void samp_kernel(const unsigned short* __restrict__ val,
                                                   const float* __restrict__ locs,
                                                   const float* __restrict__ aw,
                                                   unsigned short* __restrict__ wsum) {
    __shared__ __align__(16) float swgt[4][192][4];
    __shared__ __align__(16) int   soff[4][192][4];
    int t = threadIdx.x, wv = t >> 6, lane = t & 63;
    int q = blockIdx.x * 4 + wv;
    int b = q >> 12;
#pragma unroll
    for (int j = 0; j < 3; ++j) {
        int s = lane + 64*j;
        float2 xy = *(const float2*)&locs[(size_t)q*384 + 2*s];
        float w = aw[(size_t)q*192 + s];
        float gx = (xy.x + 1.0f)*48.0f - 0.5f;
        float gy = (xy.y + 1.0f)*32.0f - 0.5f;
        float x0f = floorf(gx), y0f = floorf(gy);
        float wx = gx - x0f, wy = gy - y0f;
        int ix = (int)x0f, iy = (int)y0f;
        bool vx0 = (unsigned)ix       < (unsigned)Ww;
        bool vx1 = (unsigned)(ix + 1) < (unsigned)Ww;
        bool vy0 = (unsigned)iy       < (unsigned)Hh;
        bool vy1 = (unsigned)(iy + 1) < (unsigned)Hh;
        int ix0 = min(max(ix, 0), Ww-1), ix1 = min(max(ix+1, 0), Ww-1);
        int iy0 = min(max(iy, 0), Hh-1), iy1 = min(max(iy+1, 0), Hh-1);
        swgt[wv][s][0] = (vx0 && vy0) ? w*(1.0f-wx)*(1.0f-wy) : 0.0f;
        swgt[wv][s][1] = (vx1 && vy0) ? w*wx*(1.0f-wy)        : 0.0f;
        swgt[wv][s][2] = (vx0 && vy1) ? w*(1.0f-wx)*wy        : 0.0f;
        swgt[wv][s][3] = (vx1 && vy1) ? w*wx*wy               : 0.0f;
        soff[wv][s][0] = (iy0*Ww + ix0) * 512;
        soff[wv][s][1] = (iy0*Ww + ix1) * 512;
        soff[wv][s][2] = (iy1*Ww + ix0) * 512;
        soff[wv][s][3] = (iy1*Ww + ix1) * 512;
    }
    __syncthreads();
    int head = lane >> 3;
    int c = head*32 + (lane & 7)*4;
    const char* vbase = (const char*)val + (size_t)b*Nn*HW*512 + c*2;
    float a0 = 0.f, a1 = 0.f, a2 = 0.f, a3 = 0.f;
    for (int n = 0; n < Nn; ++n) {
        const char* vb = vbase + (size_t)n*HW*512;
#pragma unroll
        for (int p = 0; p < POINTS; ++p) {
            int s = (n*HEADS + head)*POINTS + p;
            float4 w4 = *(const float4*)&swgt[wv][s][0];
            int4   o4 = *(const int4*)&soff[wv][s][0];
            {
                uint2 u = *(const uint2*)(vb + o4.x); float w = w4.x;
                a0 += w*bflo(u.x); a1 += w*bfhi(u.x); a2 += w*bflo(u.y); a3 += w*bfhi(u.y);
            }
            {
                uint2 u = *(const uint2*)(vb + o4.y); float w = w4.y;
                a0 += w*bflo(u.x); a1 += w*bfhi(u.x); a2 += w*bflo(u.y); a3 += w*bfhi(u.y);
            }
            {
                uint2 u = *(const uint2*)(vb + o4.z); float w = w4.z;
                a0 += w*bflo(u.x); a1 += w*bfhi(u.x); a2 += w*bflo(u.y); a3 += w*bfhi(u.y);
            }
            {
                uint2 u = *(const uint2*)(vb + o4.w); float w = w4.w;
                a0 += w*bflo(u.x); a1 += w*bfhi(u.x); a2 += w*bflo(u.y); a3 += w*bfhi(u.y);
            }
        }
    }
    uint2 o;
    o.x = (unsigned)f2bf(a0) | ((unsigned)f2bf(a1) << 16);
    o.y = (unsigned)f2bf(a2) | ((unsigned)f2bf(a3) << 16);
    *(uint2*)&wsum[(size_t)q*256 + c] = o;
}

// ---------------------------------------------------------------------------
// Kernel O (MFMA, no LDS): out = wsum(bf16) @ W_out + b_out.
// Block 64 rows x 128 cols, 256 thr = 4 waves (wm = w&1, wn = w>>1).
// A-frags straight from global (wsum k-contiguous), B from WoutT (L2-hot).
// ---------------------------------------------------------------------------
__global__ __launch_bounds__(256) void out_mfma_kernel(const unsigned short* __restrict__ wsum,
                                                       const unsigned short* __restrict__ Wot,
                                                       const float* __restrict__ b_out,
                                                       float* __restrict__ out) {
    int t = threadIdx.x;
    int row0 = blockIdx.x * 64;
    int col0 = blockIdx.y * 128;
    int wave = t >> 6, lane = t & 63, quad = lane >> 4, l15 = lane & 15;
    int wm = wave & 1;
    int wn = wave >> 1;
    f32x4 acc[2][4];
#pragma unroll
    for (int i = 0; i < 2; ++i)
#pragma unroll
        for (int j = 0; j < 4; ++j) acc[i][j] = (f32x4){0.f, 0.f, 0.f, 0.f};
#pragma unroll
    for (int kk = 0; kk < 8; ++kk) {
        short8 a[2];
#pragma unroll
        for (int mt = 0; mt < 2; ++mt)
            a[mt] = *(const short8*)&wsum[(size_t)(row0 + wm*32 + mt*16 + l15)*256 + kk*32 + quad*8];
#pragma unroll
        for (int nt = 0; nt < 4; ++nt) {
            short8 bfr = *(const short8*)&Wot[(size_t)(col0 + wn*64 + nt*16 + l15)*256 + kk*32 + quad*8];
            acc[0][nt] = __builtin_amdgcn_mfma_f32_16x16x32_bf16(a[0], bfr, acc[0][nt], 0, 0, 0);
            acc[1][nt] = __builtin_amdgcn_mfma_f32_16x16x32_bf16(a[1], bfr, acc[1][nt], 0, 0, 0);
        }
    }
#pragma unroll
    for (int nt = 0; nt < 4; ++nt) {
        int col = col0 + wn*64 + nt*16 + l15;
        float bias = b_out[col];
#pragma unroll
        for (int mt = 0; mt < 2; ++mt) {
#pragma unroll
            for (int r = 0; r < 4; ++r) {
                int q = row0 + wm*32 + mt*16 + quad*4 + r;
                out[(size_t)q*256 + col] = acc[mt][nt][r] + bias;
            }
        }
    }
}

extern "C" void kernel_launch(void* const* d_in, const int* in_sizes, int n_in,
                              void* d_out, int out_size, void* d_ws, size_t ws_size,
                              hipStream_t stream) {
    const float* query  = (const float*)d_in[0];
    const float* qc     = (const float*)d_in[1];
    const float* feats  = (const float*)d_in[2];
    const float* intr   = (const float*)d_in[3];
    const float* invE   = (const float*)d_in[4];
    const float* W_off  = (const float*)d_in[5];
    const float* b_off  = (const float*)d_in[6];
    const float* W_attn = (const float*)d_in[7];
    const float* b_attn = (const float*)d_in[8];
    const float* W_val  = (const float*)d_in[9];
    const float* b_val  = (const float*)d_in[10];
    const float* W_out  = (const float*)d_in[11];
    const float* b_out  = (const float*)d_in[12];
    float* out = (float*)d_out;
    float* ws  = (float*)d_ws;
    unsigned short* val = (unsigned short*)(ws + WS_VAL);
    unsigned short* Wt  = (unsigned short*)(ws + WS_WT);
    unsigned short* Wch = (unsigned short*)(ws + WS_WCH);
    unsigned short* Wcl = (unsigned short*)(ws + WS_WCL);
    unsigned short* Wot = (unsigned short*)(ws + WS_WOT);
    float* locs = ws + WS_LOCS;
    float* aw   = ws + WS_AW;
    float* reff = ws + WS_REFF;
    unsigned short* wsum = (unsigned short*)(ws + WS_WSUM);

    hipLaunchKernelGGL(ref_kernel, dim3(BQ/256), dim3(256), 0, stream,
                       qc, intr, invE, reff);
    hipLaunchKernelGGL(cast_kernel, dim3(1088), dim3(256), 0, stream,
                       W_val, W_off, W_attn, W_out, Wt, Wch, Wcl, Wot);
    hipLaunchKernelGGL(vp_mfma_kernel, dim3(HW/64, Bb*Nn), dim3(512), 0, stream,
                       feats, Wt, b_val, val);
    hipLaunchKernelGGL(qp_kernel, dim3(BQ/32), dim3(512), 0, stream,
                       query, Wch, Wcl, b_off, b_attn, reff, locs, aw);
    hipLaunchKernelGGL(samp_kernel, dim3(BQ/4), dim3(256), 0, stream,
                       val, locs, aw, wsum);
    hipLaunchKernelGGL(out_mfma_kernel, dim3(BQ/64, 2), dim3(256), 0, stream,
                       wsum, Wot, b_out, out);
}